// Round 22
// baseline (635.957 us; speedup 1.0000x reference)
//
#include <hip/hip_runtime.h>
#include <hip/hip_bf16.h>

#define NN 8192
#define DD 256
#define GG 64
#define SS 128
#define D2 128
#define KK 8
#define CL_ITERS 10

// Stub-named kernel kept so the original mangled symbol exists in the .so.
__global__ void DynamicSubClusteringHead_77592879169750_kernel() {}

__device__ __forceinline__ float dsc_wsum(float v) {
  for (int o = 32; o > 0; o >>= 1) v += __shfl_xor(v, o);
  return v;
}

// feat = relu(LN(x@W1+b1))@W2 + b2 ; 8 rows/block, grid 1024, ~16.6 KB LDS
static __global__ void dsc_mlp(const float* x, const float* W1, const float* b1,
                               const float* ln_g, const float* ln_b,
                               const float* W2, const float* b2, float* feat)
{
  __shared__ float xs[8][DD];
  __shared__ float rs[8][DD];
  __shared__ float red1[8][4];
  __shared__ float red2[8][4];
  const int t = threadIdx.x;
  const int lane = t & 63;
  const int wid = t >> 6;
  const int row0 = blockIdx.x * 8;

  for (int r = 0; r < 8; ++r) xs[r][t] = x[(size_t)(row0 + r) * DD + t];
  __syncthreads();

  float acc[8];
  float bb = b1[t];
  for (int r = 0; r < 8; ++r) acc[r] = bb;
  for (int k = 0; k < DD; ++k) {
    float w = W1[(size_t)k * DD + t];
    for (int r = 0; r < 8; ++r) acc[r] = fmaf(xs[r][k], w, acc[r]);
  }
  for (int r = 0; r < 8; ++r) {
    float s = dsc_wsum(acc[r]);
    if (lane == 0) red1[r][wid] = s;
  }
  __syncthreads();
  float g = ln_g[t];
  float be = ln_b[t];
  float mu[8];
  for (int r = 0; r < 8; ++r)
    mu[r] = (red1[r][0] + red1[r][1] + red1[r][2] + red1[r][3]) * (1.0f / 256.0f);
  for (int r = 0; r < 8; ++r) {
    float d = acc[r] - mu[r];
    float s = dsc_wsum(d * d);
    if (lane == 0) red2[r][wid] = s;
  }
  __syncthreads();
  for (int r = 0; r < 8; ++r) {
    float var = (red2[r][0] + red2[r][1] + red2[r][2] + red2[r][3]) * (1.0f / 256.0f);
    float hn = (acc[r] - mu[r]) / sqrtf(var + 1e-5f) * g + be;
    rs[r][t] = fmaxf(hn, 0.0f);
  }
  __syncthreads();

  const int j = t & 127;
  const int rb = (t >> 7) * 4;
  float f0 = b2[j];
  float f1 = f0, f2 = f0, f3 = f0;
  for (int k = 0; k < DD; ++k) {
    float w = W2[(size_t)k * D2 + j];
    f0 = fmaf(rs[rb + 0][k], w, f0);
    f1 = fmaf(rs[rb + 1][k], w, f1);
    f2 = fmaf(rs[rb + 2][k], w, f2);
    f3 = fmaf(rs[rb + 3][k], w, f3);
  }
  feat[(size_t)(row0 + rb + 0) * D2 + j] = f0;
  feat[(size_t)(row0 + rb + 1) * D2 + j] = f1;
  feat[(size_t)(row0 + rb + 2) * D2 + j] = f2;
  feat[(size_t)(row0 + rb + 3) * D2 + j] = f3;
}

// per-group clustering; grid 64, block 256, ~15 KB LDS; fg/cg from global (L2)
static __global__ void dsc_cluster(const float* feat, const float* comp,
                                   const float* temp, int* glob)
{
  __shared__ float Cc[KK][D2 + 1];
  __shared__ float pM[SS][KK + 1];
  __shared__ float qM[SS][KK + 1];
  __shared__ float nrm[SS];
  __shared__ float mind[SS];
  __shared__ float cn[KK];
  __shared__ float colsum[KK];
  __shared__ float cntf[KK];
  __shared__ int   asg[SS];
  __shared__ int   farp;

  const int t = threadIdx.x;
  const int gid = blockIdx.x;
  const float T = temp[0];
  const float* fg = feat + (size_t)gid * SS * D2;
  const float* cgp = comp + (size_t)(gid * SS) * NN + (size_t)gid * SS;

  for (int d = t; d < D2; d += 256) Cc[0][d] = fg[d];
  if (t < SS) {
    const float* row = fg + t * D2;
    float s = 0.0f;
    for (int d = 0; d < D2; ++d) s = fmaf(row[d], row[d], s);
    nrm[t] = s;
  }
  __syncthreads();

  // farthest-point init; compare sqrt'd distances exactly like the reference
  if (t < SS) {
    const float* row = fg + t * D2;
    float dot = 0.0f;
    for (int d = 0; d < D2; ++d) dot = fmaf(row[d], Cc[0][d], dot);
    mind[t] = sqrtf(fmaxf(nrm[t] + nrm[0] - 2.0f * dot, 0.0f));
  }
  __syncthreads();
  for (int kk = 1; kk < KK; ++kk) {
    if (t == 0) {
      float best = mind[0];
      int bi = 0;
      for (int i = 1; i < SS; ++i) {
        if (mind[i] > best) { best = mind[i]; bi = i; }
      }
      farp = bi;
    }
    __syncthreads();
    const int fi = farp;
    for (int d = t; d < D2; d += 256) Cc[kk][d] = fg[fi * D2 + d];
    __syncthreads();
    if (t < SS) {
      const float* row = fg + t * D2;
      float dot = 0.0f;
      for (int d = 0; d < D2; ++d) dot = fmaf(row[d], Cc[kk][d], dot);
      float dd = sqrtf(fmaxf(nrm[t] + nrm[fi] - 2.0f * dot, 0.0f));
      if (dd < mind[t]) mind[t] = dd;
    }
    __syncthreads();
  }

  const int ri = t >> 1;
  const int kb = (t & 1) * 4;
  for (int it = 0; it < CL_ITERS; ++it) {
    if (t < KK) {
      float s = 0.0f;
      for (int d = 0; d < D2; ++d) s = fmaf(Cc[t][d], Cc[t][d], s);
      cn[t] = s;
    }
    __syncthreads();
    {
      const float* row = fg + ri * D2;
      float d0 = 0.0f, d1 = 0.0f, d2 = 0.0f, d3 = 0.0f;
      for (int d = 0; d < D2; ++d) {
        float v = row[d];
        d0 = fmaf(v, Cc[kb + 0][d], d0);
        d1 = fmaf(v, Cc[kb + 1][d], d1);
        d2 = fmaf(v, Cc[kb + 2][d], d2);
        d3 = fmaf(v, Cc[kb + 3][d], d3);
      }
      float nr = nrm[ri];
      pM[ri][kb + 0] = -sqrtf(fmaxf(nr + cn[kb + 0] - 2.0f * d0, 0.0f)) / T;
      pM[ri][kb + 1] = -sqrtf(fmaxf(nr + cn[kb + 1] - 2.0f * d1, 0.0f)) / T;
      pM[ri][kb + 2] = -sqrtf(fmaxf(nr + cn[kb + 2] - 2.0f * d2, 0.0f)) / T;
      pM[ri][kb + 3] = -sqrtf(fmaxf(nr + cn[kb + 3] - 2.0f * d3, 0.0f)) / T;
    }
    __syncthreads();
    if (t < SS) {  // jax.nn.softmax: max-subtract, exp, divide
      float m = pM[t][0];
      for (int k = 1; k < KK; ++k) m = fmaxf(m, pM[t][k]);
      float e[KK];
      float s = 0.0f;
      for (int k = 0; k < KK; ++k) { e[k] = expf(pM[t][k] - m); s += e[k]; }
      for (int k = 0; k < KK; ++k) pM[t][k] = e[k] / s;
    }
    __syncthreads();
    if (t < KK) {
      float s = 0.0f;
      for (int i = 0; i < SS; ++i) s += pM[i][t];
      colsum[t] = s + 1e-6f;
    }
    __syncthreads();
    {
      const float* crow = cgp + (size_t)ri * NN;
      float d0 = 0.0f, d1 = 0.0f, d2 = 0.0f, d3 = 0.0f;
      for (int j = 0; j < SS; ++j) {
        float v = crow[j];
        d0 = fmaf(v, pM[j][kb + 0], d0);
        d1 = fmaf(v, pM[j][kb + 1], d1);
        d2 = fmaf(v, pM[j][kb + 2], d2);
        d3 = fmaf(v, pM[j][kb + 3], d3);
      }
      qM[ri][kb + 0] = pM[ri][kb + 0] * expf(-(d0 / colsum[kb + 0]));
      qM[ri][kb + 1] = pM[ri][kb + 1] * expf(-(d1 / colsum[kb + 1]));
      qM[ri][kb + 2] = pM[ri][kb + 2] * expf(-(d2 / colsum[kb + 2]));
      qM[ri][kb + 3] = pM[ri][kb + 3] * expf(-(d3 / colsum[kb + 3]));
    }
    __syncthreads();
    if (t < SS) {  // row-normalize like the reference, first-index argmax
      float rsum = 0.0f;
      for (int k = 0; k < KK; ++k) rsum += qM[t][k];
      rsum += 1e-6f;
      float best = qM[t][0] / rsum;
      int bi = 0;
      for (int k = 1; k < KK; ++k) {
        float v = qM[t][k] / rsum;
        if (v > best) { best = v; bi = k; }
      }
      asg[t] = bi;
    }
    __syncthreads();
    if (t < KK) {
      int c = 0;
      for (int i = 0; i < SS; ++i) { if (asg[i] == t) ++c; }
      cntf[t] = (float)c;
    }
    __syncthreads();
    for (int task = t; task < KK * D2; task += 256) {
      int k = task >> 7;
      int d = task & 127;
      if (cntf[k] > 0.0f) {
        float s = 0.0f;
        for (int i = 0; i < SS; ++i) { if (asg[i] == k) s += fg[i * D2 + d]; }
        Cc[k][d] = s / fmaxf(cntf[k], 1.0f);
      }
    }
    __syncthreads();
  }

  if (t < SS) glob[gid * SS + t] = asg[t] + gid * KK;
}

// labels: out[0..NN) = (float)glob[i]   -- OUTPUT IS FLOAT32
static __global__ void dsc_labels(const int* glob, float* out)
{
  int i = blockIdx.x * blockDim.x + threadIdx.x;
  if (i < NN) out[i] = (float)glob[i];
}

// P[i][j] = (glob[i]==glob[j]) ? 1.0f : 0.0f ; float4 stores, 8 rows/block.
// Skips f32-element window [e_lo, e_hi) (0,0 = disabled; fallback scratch).
static __global__ void dsc_pmat(const int* glob, float* out,
                                unsigned long long e_lo, unsigned long long e_hi)
{
  __shared__ __align__(8) unsigned short gl16[NN];  // 16 KB
  const int t = threadIdx.x;
  for (int i = t; i < NN; i += 256) gl16[i] = (unsigned short)glob[i];
  __syncthreads();
  const int row0 = blockIdx.x * 8;
  const uint2* gv = (const uint2*)gl16;  // 4 labels per uint2
  for (int r = 0; r < 8; ++r) {
    const int row = row0 + r;
    const unsigned int lab = (unsigned int)gl16[row];
    const unsigned long long ebase =
        (unsigned long long)NN + (unsigned long long)row * NN;
    for (int v = t; v < NN / 4; v += 256) {
      uint2 g4 = gv[v];
      float4 o;
      o.x = ((g4.x & 0xFFFFu) == lab) ? 1.0f : 0.0f;
      o.y = ((g4.x >> 16) == lab) ? 1.0f : 0.0f;
      o.z = ((g4.y & 0xFFFFu) == lab) ? 1.0f : 0.0f;
      o.w = ((g4.y >> 16) == lab) ? 1.0f : 0.0f;
      unsigned long long e = ebase + (unsigned long long)v * 4ull;
      if (!(e < e_hi && e + 4ull > e_lo)) {
        *(float4*)(out + e) = o;
      }
    }
  }
}

// fallback-only: patch the skip window (grid 1; glob snapshot in LDS first)
static __global__ void dsc_fix(const int* glob, float* out,
                               unsigned long long e_lo, unsigned long long e_hi)
{
  __shared__ int gl[NN];  // 32 KB
  const int t = threadIdx.x;
  for (int i = t; i < NN; i += 256) gl[i] = glob[i];
  __syncthreads();
  for (unsigned long long e = e_lo + (unsigned long long)t; e < e_hi; e += 256ull) {
    if (e < (unsigned long long)NN) {
      out[e] = (float)gl[e];
    } else {
      unsigned long long pf = e - (unsigned long long)NN;
      int i = (int)(pf >> 13);
      int j = (int)(pf & 8191ull);
      out[e] = (gl[i] == gl[j]) ? 1.0f : 0.0f;
    }
  }
}

extern "C" void kernel_launch(void* const* d_in, const int* in_sizes, int n_in,
                              void* d_out, int out_size, void* d_ws, size_t ws_size,
                              hipStream_t stream) {
  (void)in_sizes;
  (void)n_in;
  const float* x    = (const float*)d_in[0];
  // d_in[1] = lv_group_ids: unused by the reference computation
  const float* comp = (const float*)d_in[2];
  const float* W1   = (const float*)d_in[3];
  const float* b1   = (const float*)d_in[4];
  const float* ln_g = (const float*)d_in[5];
  const float* ln_b = (const float*)d_in[6];
  const float* W2   = (const float*)d_in[7];
  const float* b2   = (const float*)d_in[8];
  const float* temp = (const float*)d_in[9];

  float* out = (float*)d_out;                       // FLOAT32 output buffer
  char* outc = (char*)d_out;
  const size_t out_bytes  = (size_t)out_size * 4u;  // f32: ~268 MB
  const size_t feat_bytes = (size_t)NN * D2 * 4u;   // 4 MB
  const size_t glob_bytes = (size_t)NN * 4u;        // 32 KB
  const size_t scratch_bytes = feat_bytes + glob_bytes;

  float* feat;
  int* glob;
  unsigned long long e_lo = 0ull, e_hi = 0ull;
  int need_fix = 0;
  if (ws_size >= scratch_bytes) {
    feat = (float*)d_ws;
    glob = (int*)((char*)d_ws + feat_bytes);
  } else {
    // carve from d_out's tail; pmat skips the glob window, dsc_fix patches it
    feat = (float*)(outc + out_bytes - glob_bytes - feat_bytes);
    glob = (int*)(outc + out_bytes - glob_bytes);
    e_lo = (unsigned long long)(out_size - NN);
    e_hi = (unsigned long long)out_size;
    need_fix = 1;
  }

  dsc_mlp<<<NN / 8, 256, 0, stream>>>(x, W1, b1, ln_g, ln_b, W2, b2, feat);
  dsc_cluster<<<GG, 256, 0, stream>>>(feat, comp, temp, glob);
  dsc_labels<<<(NN + 255) / 256, 256, 0, stream>>>(glob, out);
  dsc_pmat<<<NN / 8, 256, 0, stream>>>(glob, out, e_lo, e_hi);
  if (need_fix) {
    dsc_fix<<<1, 256, 0, stream>>>(glob, out, e_lo, e_hi);
  }
}

// Round 23
// 377.270 us; speedup vs baseline: 1.6857x; 1.6857x over previous
//
#include <hip/hip_runtime.h>
#include <hip/hip_bf16.h>

#define NN 8192
#define DD 256
#define GG 64
#define SS 128
#define D2 128
#define KK 8
#define CL_ITERS 10

// Stub-named kernel kept so the original mangled symbol exists in the .so.
__global__ void DynamicSubClusteringHead_77592879169750_kernel() {}

__device__ __forceinline__ float dsc_wsum(float v) {
  for (int o = 32; o > 0; o >>= 1) v += __shfl_xor(v, o);
  return v;
}

// feat = relu(LN(x@W1+b1))@W2 + b2 ; 8 rows/block, grid 1024, ~16.6 KB LDS
static __global__ void dsc_mlp(const float* x, const float* W1, const float* b1,
                               const float* ln_g, const float* ln_b,
                               const float* W2, const float* b2, float* feat)
{
  __shared__ float xs[8][DD];
  __shared__ float rs[8][DD];
  __shared__ float red1[8][4];
  __shared__ float red2[8][4];
  const int t = threadIdx.x;
  const int lane = t & 63;
  const int wid = t >> 6;
  const int row0 = blockIdx.x * 8;

  for (int r = 0; r < 8; ++r) xs[r][t] = x[(size_t)(row0 + r) * DD + t];
  __syncthreads();

  float acc[8];
  float bb = b1[t];
  for (int r = 0; r < 8; ++r) acc[r] = bb;
  for (int k = 0; k < DD; ++k) {
    float w = W1[(size_t)k * DD + t];
    for (int r = 0; r < 8; ++r) acc[r] = fmaf(xs[r][k], w, acc[r]);
  }
  for (int r = 0; r < 8; ++r) {
    float s = dsc_wsum(acc[r]);
    if (lane == 0) red1[r][wid] = s;
  }
  __syncthreads();
  float g = ln_g[t];
  float be = ln_b[t];
  float mu[8];
  for (int r = 0; r < 8; ++r)
    mu[r] = (red1[r][0] + red1[r][1] + red1[r][2] + red1[r][3]) * (1.0f / 256.0f);
  for (int r = 0; r < 8; ++r) {
    float d = acc[r] - mu[r];
    float s = dsc_wsum(d * d);
    if (lane == 0) red2[r][wid] = s;
  }
  __syncthreads();
  for (int r = 0; r < 8; ++r) {
    float var = (red2[r][0] + red2[r][1] + red2[r][2] + red2[r][3]) * (1.0f / 256.0f);
    float hn = (acc[r] - mu[r]) / sqrtf(var + 1e-5f) * g + be;
    rs[r][t] = fmaxf(hn, 0.0f);
  }
  __syncthreads();

  const int j = t & 127;
  const int rb = (t >> 7) * 4;
  float f0 = b2[j];
  float f1 = f0, f2 = f0, f3 = f0;
  for (int k = 0; k < DD; ++k) {
    float w = W2[(size_t)k * D2 + j];
    f0 = fmaf(rs[rb + 0][k], w, f0);
    f1 = fmaf(rs[rb + 1][k], w, f1);
    f2 = fmaf(rs[rb + 2][k], w, f2);
    f3 = fmaf(rs[rb + 3][k], w, f3);
  }
  feat[(size_t)(row0 + rb + 0) * D2 + j] = f0;
  feat[(size_t)(row0 + rb + 1) * D2 + j] = f1;
  feat[(size_t)(row0 + rb + 2) * D2 + j] = f2;
  feat[(size_t)(row0 + rb + 3) * D2 + j] = f3;
}

// per-group clustering; grid 64, block 1024 (16 waves/CU for latency hiding).
// Thread roles: (ri, kc) = (t>>3, t&7) for distance/q phases;
//               (kc2, dc) = (t>>7, t&127) for the center update.
// All accumulation chains preserve the exact fmaf order of the passing
// 256-thread version (ascending d / j / i) for bit-identical partitions.
static __global__ __launch_bounds__(1024) void dsc_cluster(
    const float* feat, const float* comp, const float* temp, int* glob)
{
  __shared__ float Cc[KK][D2 + 1];
  __shared__ float pM[SS][KK + 1];
  __shared__ float qM[SS][KK + 1];
  __shared__ float nrm[SS];
  __shared__ float mind[SS];
  __shared__ float cn[KK];
  __shared__ float colsum[KK];
  __shared__ float cntf[KK];
  __shared__ int   asg[SS];
  __shared__ int   farp;

  const int t = threadIdx.x;
  const int gid = blockIdx.x;
  const float T = temp[0];
  const float* fg = feat + (size_t)gid * SS * D2;
  const float* cgp = comp + (size_t)(gid * SS) * NN + (size_t)gid * SS;

  for (int d = t; d < D2; d += 1024) Cc[0][d] = fg[d];
  if (t < SS) {
    const float* row = fg + t * D2;
    float s = 0.0f;
    for (int d = 0; d < D2; ++d) s = fmaf(row[d], row[d], s);
    nrm[t] = s;
  }
  __syncthreads();

  // farthest-point init; compare sqrt'd distances exactly like the reference
  if (t < SS) {
    const float* row = fg + t * D2;
    float dot = 0.0f;
    for (int d = 0; d < D2; ++d) dot = fmaf(row[d], Cc[0][d], dot);
    mind[t] = sqrtf(fmaxf(nrm[t] + nrm[0] - 2.0f * dot, 0.0f));
  }
  __syncthreads();
  for (int kk = 1; kk < KK; ++kk) {
    if (t == 0) {
      float best = mind[0];
      int bi = 0;
      for (int i = 1; i < SS; ++i) {
        if (mind[i] > best) { best = mind[i]; bi = i; }
      }
      farp = bi;
    }
    __syncthreads();
    const int fi = farp;
    for (int d = t; d < D2; d += 1024) Cc[kk][d] = fg[fi * D2 + d];
    __syncthreads();
    if (t < SS) {
      const float* row = fg + t * D2;
      float dot = 0.0f;
      for (int d = 0; d < D2; ++d) dot = fmaf(row[d], Cc[kk][d], dot);
      float dd = sqrtf(fmaxf(nrm[t] + nrm[fi] - 2.0f * dot, 0.0f));
      if (dd < mind[t]) mind[t] = dd;
    }
    __syncthreads();
  }

  const int ri = t >> 3;        // row for distance/q phases
  const int kc = t & 7;         // center for distance/q phases
  const int kc2 = t >> 7;       // center for the update phase
  const int dc  = t & 127;      // dim for the update phase
  for (int it = 0; it < CL_ITERS; ++it) {
    if (t < KK) {
      float s = 0.0f;
      for (int d = 0; d < D2; ++d) s = fmaf(Cc[t][d], Cc[t][d], s);
      cn[t] = s;
    }
    __syncthreads();
    // logits: one (row, center) per thread; ascending-d fmaf chain
    {
      const float* row = fg + ri * D2;
      float s = 0.0f;
      for (int d = 0; d < D2; ++d) s = fmaf(row[d], Cc[kc][d], s);
      pM[ri][kc] = -sqrtf(fmaxf(nrm[ri] + cn[kc] - 2.0f * s, 0.0f)) / T;
    }
    __syncthreads();
    if (t < SS) {  // jax.nn.softmax: max-subtract, exp, divide
      float m = pM[t][0];
      for (int k = 1; k < KK; ++k) m = fmaxf(m, pM[t][k]);
      float e[KK];
      float s = 0.0f;
      for (int k = 0; k < KK; ++k) { e[k] = expf(pM[t][k] - m); s += e[k]; }
      for (int k = 0; k < KK; ++k) pM[t][k] = e[k] / s;
    }
    __syncthreads();
    if (t < KK) {
      float s = 0.0f;
      for (int i = 0; i < SS; ++i) s += pM[i][t];
      colsum[t] = s + 1e-6f;
    }
    __syncthreads();
    // q = p * exp(-(cg@p)/colsum): one (row, center) per thread
    {
      const float* crow = cgp + (size_t)ri * NN;
      float s = 0.0f;
      for (int j = 0; j < SS; ++j) s = fmaf(crow[j], pM[j][kc], s);
      qM[ri][kc] = pM[ri][kc] * expf(-(s / colsum[kc]));
    }
    __syncthreads();
    if (t < SS) {  // row-normalize like the reference, first-index argmax
      float rsum = 0.0f;
      for (int k = 0; k < KK; ++k) rsum += qM[t][k];
      rsum += 1e-6f;
      float best = qM[t][0] / rsum;
      int bi = 0;
      for (int k = 1; k < KK; ++k) {
        float v = qM[t][k] / rsum;
        if (v > best) { best = v; bi = k; }
      }
      asg[t] = bi;
    }
    __syncthreads();
    if (t < KK) {
      int c = 0;
      for (int i = 0; i < SS; ++i) { if (asg[i] == t) ++c; }
      cntf[t] = (float)c;
    }
    __syncthreads();
    // center update: thread (kc2, dc); UNCONDITIONAL loads (pipelineable),
    // predicated add preserves the exact ascending-i conditional sum.
    {
      float s = 0.0f;
      for (int i = 0; i < SS; ++i) {
        float v = fg[i * D2 + dc];
        if (asg[i] == kc2) s += v;
      }
      if (cntf[kc2] > 0.0f) {
        Cc[kc2][dc] = s / fmaxf(cntf[kc2], 1.0f);
      }
    }
    __syncthreads();
  }

  if (t < SS) glob[gid * SS + t] = asg[t] + gid * KK;
}

// labels: out[0..NN) = (float)glob[i]   -- OUTPUT IS FLOAT32
static __global__ void dsc_labels(const int* glob, float* out)
{
  int i = blockIdx.x * blockDim.x + threadIdx.x;
  if (i < NN) out[i] = (float)glob[i];
}

// P[i][j] = (glob[i]==glob[j]) ? 1.0f : 0.0f ; float4 stores, 8 rows/block.
// Skips f32-element window [e_lo, e_hi) (0,0 = disabled; fallback scratch).
static __global__ void dsc_pmat(const int* glob, float* out,
                                unsigned long long e_lo, unsigned long long e_hi)
{
  __shared__ __align__(8) unsigned short gl16[NN];  // 16 KB
  const int t = threadIdx.x;
  for (int i = t; i < NN; i += 256) gl16[i] = (unsigned short)glob[i];
  __syncthreads();
  const int row0 = blockIdx.x * 8;
  const uint2* gv = (const uint2*)gl16;  // 4 labels per uint2
  for (int r = 0; r < 8; ++r) {
    const int row = row0 + r;
    const unsigned int lab = (unsigned int)gl16[row];
    const unsigned long long ebase =
        (unsigned long long)NN + (unsigned long long)row * NN;
    for (int v = t; v < NN / 4; v += 256) {
      uint2 g4 = gv[v];
      float4 o;
      o.x = ((g4.x & 0xFFFFu) == lab) ? 1.0f : 0.0f;
      o.y = ((g4.x >> 16) == lab) ? 1.0f : 0.0f;
      o.z = ((g4.y & 0xFFFFu) == lab) ? 1.0f : 0.0f;
      o.w = ((g4.y >> 16) == lab) ? 1.0f : 0.0f;
      unsigned long long e = ebase + (unsigned long long)v * 4ull;
      if (!(e < e_hi && e + 4ull > e_lo)) {
        *(float4*)(out + e) = o;
      }
    }
  }
}

// fallback-only: patch the skip window (grid 1; glob snapshot in LDS first)
static __global__ void dsc_fix(const int* glob, float* out,
                               unsigned long long e_lo, unsigned long long e_hi)
{
  __shared__ int gl[NN];  // 32 KB
  const int t = threadIdx.x;
  for (int i = t; i < NN; i += 256) gl[i] = glob[i];
  __syncthreads();
  for (unsigned long long e = e_lo + (unsigned long long)t; e < e_hi; e += 256ull) {
    if (e < (unsigned long long)NN) {
      out[e] = (float)gl[e];
    } else {
      unsigned long long pf = e - (unsigned long long)NN;
      int i = (int)(pf >> 13);
      int j = (int)(pf & 8191ull);
      out[e] = (gl[i] == gl[j]) ? 1.0f : 0.0f;
    }
  }
}

extern "C" void kernel_launch(void* const* d_in, const int* in_sizes, int n_in,
                              void* d_out, int out_size, void* d_ws, size_t ws_size,
                              hipStream_t stream) {
  (void)in_sizes;
  (void)n_in;
  const float* x    = (const float*)d_in[0];
  // d_in[1] = lv_group_ids: unused by the reference computation
  const float* comp = (const float*)d_in[2];
  const float* W1   = (const float*)d_in[3];
  const float* b1   = (const float*)d_in[4];
  const float* ln_g = (const float*)d_in[5];
  const float* ln_b = (const float*)d_in[6];
  const float* W2   = (const float*)d_in[7];
  const float* b2   = (const float*)d_in[8];
  const float* temp = (const float*)d_in[9];

  float* out = (float*)d_out;                       // FLOAT32 output buffer
  char* outc = (char*)d_out;
  const size_t out_bytes  = (size_t)out_size * 4u;  // f32: ~268 MB
  const size_t feat_bytes = (size_t)NN * D2 * 4u;   // 4 MB
  const size_t glob_bytes = (size_t)NN * 4u;        // 32 KB
  const size_t scratch_bytes = feat_bytes + glob_bytes;

  float* feat;
  int* glob;
  unsigned long long e_lo = 0ull, e_hi = 0ull;
  int need_fix = 0;
  if (ws_size >= scratch_bytes) {
    feat = (float*)d_ws;
    glob = (int*)((char*)d_ws + feat_bytes);
  } else {
    // carve from d_out's tail; pmat skips the glob window, dsc_fix patches it
    feat = (float*)(outc + out_bytes - glob_bytes - feat_bytes);
    glob = (int*)(outc + out_bytes - glob_bytes);
    e_lo = (unsigned long long)(out_size - NN);
    e_hi = (unsigned long long)out_size;
    need_fix = 1;
  }

  dsc_mlp<<<NN / 8, 256, 0, stream>>>(x, W1, b1, ln_g, ln_b, W2, b2, feat);
  dsc_cluster<<<GG, 1024, 0, stream>>>(feat, comp, temp, glob);
  dsc_labels<<<(NN + 255) / 256, 256, 0, stream>>>(glob, out);
  dsc_pmat<<<NN / 8, 256, 0, stream>>>(glob, out, e_lo, e_hi);
  if (need_fix) {
    dsc_fix<<<1, 256, 0, stream>>>(glob, out, e_lo, e_hi);
  }
}

// Round 24
// 341.758 us; speedup vs baseline: 1.8608x; 1.1039x over previous
//
#include <hip/hip_runtime.h>
#include <hip/hip_bf16.h>

#define NN 8192
#define DD 256
#define GG 64
#define SS 128
#define D2 128
#define KK 8
#define CL_ITERS 10
#define LDSP 129   // padded row stride (floats) for bank-conflict-free LDS

// Stub-named kernel kept so the original mangled symbol exists in the .so.
__global__ void DynamicSubClusteringHead_77592879169750_kernel() {}

__device__ __forceinline__ float dsc_wsum(float v) {
  for (int o = 32; o > 0; o >>= 1) v += __shfl_xor(v, o);
  return v;
}

// feat = relu(LN(x@W1+b1))@W2 + b2 ; 8 rows/block, grid 1024, ~16.6 KB LDS
static __global__ void dsc_mlp(const float* x, const float* W1, const float* b1,
                               const float* ln_g, const float* ln_b,
                               const float* W2, const float* b2, float* feat)
{
  __shared__ float xs[8][DD];
  __shared__ float rs[8][DD];
  __shared__ float red1[8][4];
  __shared__ float red2[8][4];
  const int t = threadIdx.x;
  const int lane = t & 63;
  const int wid = t >> 6;
  const int row0 = blockIdx.x * 8;

  for (int r = 0; r < 8; ++r) xs[r][t] = x[(size_t)(row0 + r) * DD + t];
  __syncthreads();

  float acc[8];
  float bb = b1[t];
  for (int r = 0; r < 8; ++r) acc[r] = bb;
  for (int k = 0; k < DD; ++k) {
    float w = W1[(size_t)k * DD + t];
    for (int r = 0; r < 8; ++r) acc[r] = fmaf(xs[r][k], w, acc[r]);
  }
  for (int r = 0; r < 8; ++r) {
    float s = dsc_wsum(acc[r]);
    if (lane == 0) red1[r][wid] = s;
  }
  __syncthreads();
  float g = ln_g[t];
  float be = ln_b[t];
  float mu[8];
  for (int r = 0; r < 8; ++r)
    mu[r] = (red1[r][0] + red1[r][1] + red1[r][2] + red1[r][3]) * (1.0f / 256.0f);
  for (int r = 0; r < 8; ++r) {
    float d = acc[r] - mu[r];
    float s = dsc_wsum(d * d);
    if (lane == 0) red2[r][wid] = s;
  }
  __syncthreads();
  for (int r = 0; r < 8; ++r) {
    float var = (red2[r][0] + red2[r][1] + red2[r][2] + red2[r][3]) * (1.0f / 256.0f);
    float hn = (acc[r] - mu[r]) / sqrtf(var + 1e-5f) * g + be;
    rs[r][t] = fmaxf(hn, 0.0f);
  }
  __syncthreads();

  const int j = t & 127;
  const int rb = (t >> 7) * 4;
  float f0 = b2[j];
  float f1 = f0, f2 = f0, f3 = f0;
  for (int k = 0; k < DD; ++k) {
    float w = W2[(size_t)k * D2 + j];
    f0 = fmaf(rs[rb + 0][k], w, f0);
    f1 = fmaf(rs[rb + 1][k], w, f1);
    f2 = fmaf(rs[rb + 2][k], w, f2);
    f3 = fmaf(rs[rb + 3][k], w, f3);
  }
  feat[(size_t)(row0 + rb + 0) * D2 + j] = f0;
  feat[(size_t)(row0 + rb + 1) * D2 + j] = f1;
  feat[(size_t)(row0 + rb + 2) * D2 + j] = f2;
  feat[(size_t)(row0 + rb + 3) * D2 + j] = f3;
}

// per-group clustering; grid 64, block 1024; fg + comp block staged in
// dynamic LDS (2 x 128 x 129 floats = 129 KB) -> all iteration phases are
// LDS/VALU-bound. Accumulation order identical to the passing version
// (ascending d / j / i) => bit-identical partition.
static __global__ __launch_bounds__(1024) void dsc_cluster(
    const float* feat, const float* comp, const float* temp, int* glob)
{
  extern __shared__ float dyn[];
  float* fgs = dyn;                 // [SS][LDSP]
  float* cgs = dyn + SS * LDSP;     // [SS][LDSP]

  __shared__ float Cc[KK][LDSP];
  __shared__ float pM[SS][KK + 1];
  __shared__ float qM[SS][KK + 1];
  __shared__ float nrm[SS];
  __shared__ float mind[SS];
  __shared__ float cn[KK];
  __shared__ float colsum[KK];
  __shared__ float cntf[KK];
  __shared__ int   asg[SS];
  __shared__ int   farp;

  const int t = threadIdx.x;
  const int gid = blockIdx.x;
  const float T = temp[0];
  const float* fg = feat + (size_t)gid * SS * D2;
  const float* cgp = comp + (size_t)(gid * SS) * NN + (size_t)gid * SS;

  // stage fg and the group's comp block into LDS (coalesced)
  for (int idx = t; idx < SS * D2; idx += 1024) {
    int i = idx >> 7, d = idx & 127;
    fgs[i * LDSP + d] = fg[idx];
  }
  for (int idx = t; idx < SS * SS; idx += 1024) {
    int i = idx >> 7, j = idx & 127;
    cgs[i * LDSP + j] = cgp[(size_t)i * NN + j];
  }
  __syncthreads();

  for (int d = t; d < D2; d += 1024) Cc[0][d] = fgs[d];
  if (t < SS) {
    const float* row = fgs + t * LDSP;
    float s = 0.0f;
#pragma unroll 4
    for (int d = 0; d < D2; ++d) s = fmaf(row[d], row[d], s);
    nrm[t] = s;
  }
  __syncthreads();

  // farthest-point init; compare sqrt'd distances exactly like the reference
  if (t < SS) {
    const float* row = fgs + t * LDSP;
    float dot = 0.0f;
#pragma unroll 4
    for (int d = 0; d < D2; ++d) dot = fmaf(row[d], Cc[0][d], dot);
    mind[t] = sqrtf(fmaxf(nrm[t] + nrm[0] - 2.0f * dot, 0.0f));
  }
  __syncthreads();
  for (int kk = 1; kk < KK; ++kk) {
    if (t == 0) {
      float best = mind[0];
      int bi = 0;
      for (int i = 1; i < SS; ++i) {
        if (mind[i] > best) { best = mind[i]; bi = i; }
      }
      farp = bi;
    }
    __syncthreads();
    const int fi = farp;
    for (int d = t; d < D2; d += 1024) Cc[kk][d] = fgs[fi * LDSP + d];
    __syncthreads();
    if (t < SS) {
      const float* row = fgs + t * LDSP;
      float dot = 0.0f;
#pragma unroll 4
      for (int d = 0; d < D2; ++d) dot = fmaf(row[d], Cc[kk][d], dot);
      float dd = sqrtf(fmaxf(nrm[t] + nrm[fi] - 2.0f * dot, 0.0f));
      if (dd < mind[t]) mind[t] = dd;
    }
    __syncthreads();
  }

  const int ri = t >> 3;        // row for distance/q phases
  const int kc = t & 7;         // center for distance/q phases
  const int kc2 = t >> 7;       // center for the update phase
  const int dc  = t & 127;      // dim for the update phase
  for (int it = 0; it < CL_ITERS; ++it) {
    if (t < KK) {
      float s = 0.0f;
#pragma unroll 4
      for (int d = 0; d < D2; ++d) s = fmaf(Cc[t][d], Cc[t][d], s);
      cn[t] = s;
    }
    __syncthreads();
    // logits: one (row, center) per thread; ascending-d fmaf chain (LDS)
    {
      const float* row = fgs + ri * LDSP;
      const float* cen = Cc[kc];
      float s = 0.0f;
#pragma unroll 4
      for (int d = 0; d < D2; ++d) s = fmaf(row[d], cen[d], s);
      pM[ri][kc] = -sqrtf(fmaxf(nrm[ri] + cn[kc] - 2.0f * s, 0.0f)) / T;
    }
    __syncthreads();
    if (t < SS) {  // jax.nn.softmax: max-subtract, exp, divide
      float m = pM[t][0];
      for (int k = 1; k < KK; ++k) m = fmaxf(m, pM[t][k]);
      float e[KK];
      float s = 0.0f;
      for (int k = 0; k < KK; ++k) { e[k] = expf(pM[t][k] - m); s += e[k]; }
      for (int k = 0; k < KK; ++k) pM[t][k] = e[k] / s;
    }
    __syncthreads();
    if (t < KK) {
      float s = 0.0f;
      for (int i = 0; i < SS; ++i) s += pM[i][t];
      colsum[t] = s + 1e-6f;
    }
    __syncthreads();
    // q = p * exp(-(cg@p)/colsum): one (row, center) per thread (LDS)
    {
      const float* crow = cgs + ri * LDSP;
      float s = 0.0f;
#pragma unroll 4
      for (int j = 0; j < SS; ++j) s = fmaf(crow[j], pM[j][kc], s);
      qM[ri][kc] = pM[ri][kc] * expf(-(s / colsum[kc]));
    }
    __syncthreads();
    if (t < SS) {  // row-normalize like the reference, first-index argmax
      float rsum = 0.0f;
      for (int k = 0; k < KK; ++k) rsum += qM[t][k];
      rsum += 1e-6f;
      float best = qM[t][0] / rsum;
      int bi = 0;
      for (int k = 1; k < KK; ++k) {
        float v = qM[t][k] / rsum;
        if (v > best) { best = v; bi = k; }
      }
      asg[t] = bi;
    }
    __syncthreads();
    if (t < KK) {
      int c = 0;
      for (int i = 0; i < SS; ++i) { if (asg[i] == t) ++c; }
      cntf[t] = (float)c;
    }
    __syncthreads();
    // center update: thread (kc2, dc); ascending-i predicated adds (LDS)
    {
      float s = 0.0f;
      for (int i = 0; i < SS; ++i) {
        float v = fgs[i * LDSP + dc];
        if (asg[i] == kc2) s += v;
      }
      if (cntf[kc2] > 0.0f) {
        Cc[kc2][dc] = s / fmaxf(cntf[kc2], 1.0f);
      }
    }
    __syncthreads();
  }

  if (t < SS) glob[gid * SS + t] = asg[t] + gid * KK;
}

// labels: out[0..NN) = (float)glob[i]   -- OUTPUT IS FLOAT32
static __global__ void dsc_labels(const int* glob, float* out)
{
  int i = blockIdx.x * blockDim.x + threadIdx.x;
  if (i < NN) out[i] = (float)glob[i];
}

// P[i][j] = (glob[i]==glob[j]) ? 1.0f : 0.0f ; float4 stores, 8 rows/block.
// Skips f32-element window [e_lo, e_hi) (0,0 = disabled; fallback scratch).
static __global__ void dsc_pmat(const int* glob, float* out,
                                unsigned long long e_lo, unsigned long long e_hi)
{
  __shared__ __align__(8) unsigned short gl16[NN];  // 16 KB
  const int t = threadIdx.x;
  for (int i = t; i < NN; i += 256) gl16[i] = (unsigned short)glob[i];
  __syncthreads();
  const int row0 = blockIdx.x * 8;
  const uint2* gv = (const uint2*)gl16;  // 4 labels per uint2
  for (int r = 0; r < 8; ++r) {
    const int row = row0 + r;
    const unsigned int lab = (unsigned int)gl16[row];
    const unsigned long long ebase =
        (unsigned long long)NN + (unsigned long long)row * NN;
    for (int v = t; v < NN / 4; v += 256) {
      uint2 g4 = gv[v];
      float4 o;
      o.x = ((g4.x & 0xFFFFu) == lab) ? 1.0f : 0.0f;
      o.y = ((g4.x >> 16) == lab) ? 1.0f : 0.0f;
      o.z = ((g4.y & 0xFFFFu) == lab) ? 1.0f : 0.0f;
      o.w = ((g4.y >> 16) == lab) ? 1.0f : 0.0f;
      unsigned long long e = ebase + (unsigned long long)v * 4ull;
      if (!(e < e_hi && e + 4ull > e_lo)) {
        *(float4*)(out + e) = o;
      }
    }
  }
}

// fallback-only: patch the skip window (grid 1; glob snapshot in LDS first)
static __global__ void dsc_fix(const int* glob, float* out,
                               unsigned long long e_lo, unsigned long long e_hi)
{
  __shared__ int gl[NN];  // 32 KB
  const int t = threadIdx.x;
  for (int i = t; i < NN; i += 256) gl[i] = glob[i];
  __syncthreads();
  for (unsigned long long e = e_lo + (unsigned long long)t; e < e_hi; e += 256ull) {
    if (e < (unsigned long long)NN) {
      out[e] = (float)gl[e];
    } else {
      unsigned long long pf = e - (unsigned long long)NN;
      int i = (int)(pf >> 13);
      int j = (int)(pf & 8191ull);
      out[e] = (gl[i] == gl[j]) ? 1.0f : 0.0f;
    }
  }
}

extern "C" void kernel_launch(void* const* d_in, const int* in_sizes, int n_in,
                              void* d_out, int out_size, void* d_ws, size_t ws_size,
                              hipStream_t stream) {
  (void)in_sizes;
  (void)n_in;
  const float* x    = (const float*)d_in[0];
  // d_in[1] = lv_group_ids: unused by the reference computation
  const float* comp = (const float*)d_in[2];
  const float* W1   = (const float*)d_in[3];
  const float* b1   = (const float*)d_in[4];
  const float* ln_g = (const float*)d_in[5];
  const float* ln_b = (const float*)d_in[6];
  const float* W2   = (const float*)d_in[7];
  const float* b2   = (const float*)d_in[8];
  const float* temp = (const float*)d_in[9];

  float* out = (float*)d_out;                       // FLOAT32 output buffer
  char* outc = (char*)d_out;
  const size_t out_bytes  = (size_t)out_size * 4u;  // f32: ~268 MB
  const size_t feat_bytes = (size_t)NN * D2 * 4u;   // 4 MB
  const size_t glob_bytes = (size_t)NN * 4u;        // 32 KB
  const size_t scratch_bytes = feat_bytes + glob_bytes;

  float* feat;
  int* glob;
  unsigned long long e_lo = 0ull, e_hi = 0ull;
  int need_fix = 0;
  if (ws_size >= scratch_bytes) {
    feat = (float*)d_ws;
    glob = (int*)((char*)d_ws + feat_bytes);
  } else {
    // carve from d_out's tail; pmat skips the glob window, dsc_fix patches it
    feat = (float*)(outc + out_bytes - glob_bytes - feat_bytes);
    glob = (int*)(outc + out_bytes - glob_bytes);
    e_lo = (unsigned long long)(out_size - NN);
    e_hi = (unsigned long long)out_size;
    need_fix = 1;
  }

  const size_t dyn_lds = (size_t)(2 * SS * LDSP) * sizeof(float);  // 132096 B

  dsc_mlp<<<NN / 8, 256, 0, stream>>>(x, W1, b1, ln_g, ln_b, W2, b2, feat);
  dsc_cluster<<<GG, 1024, dyn_lds, stream>>>(feat, comp, temp, glob);
  dsc_labels<<<(NN + 255) / 256, 256, 0, stream>>>(glob, out);
  dsc_pmat<<<NN / 8, 256, 0, stream>>>(glob, out, e_lo, e_hi);
  if (need_fix) {
    dsc_fix<<<1, 256, 0, stream>>>(glob, out, e_lo, e_hi);
  }
}

// Round 25
// 288.264 us; speedup vs baseline: 2.2062x; 1.1856x over previous
//
#include <hip/hip_runtime.h>
#include <hip/hip_bf16.h>

#define NN 8192
#define DD 256
#define GG 64
#define SS 128
#define D2 128
#define KK 8
#define CL_ITERS 10
#define LDSP 129   // padded row stride (floats) for bank-conflict-free LDS

// Stub-named kernel kept so the original mangled symbol exists in the .so.
__global__ void DynamicSubClusteringHead_77592879169750_kernel() {}

__device__ __forceinline__ float dsc_wsum(float v) {
  for (int o = 32; o > 0; o >>= 1) v += __shfl_xor(v, o);
  return v;
}

// feat = relu(LN(x@W1+b1))@W2 + b2 ; 8 rows/block, grid 1024, ~16.6 KB LDS
static __global__ void dsc_mlp(const float* x, const float* W1, const float* b1,
                               const float* ln_g, const float* ln_b,
                               const float* W2, const float* b2, float* feat)
{
  __shared__ float xs[8][DD];
  __shared__ float rs[8][DD];
  __shared__ float red1[8][4];
  __shared__ float red2[8][4];
  const int t = threadIdx.x;
  const int lane = t & 63;
  const int wid = t >> 6;
  const int row0 = blockIdx.x * 8;

  for (int r = 0; r < 8; ++r) xs[r][t] = x[(size_t)(row0 + r) * DD + t];
  __syncthreads();

  float acc[8];
  float bb = b1[t];
  for (int r = 0; r < 8; ++r) acc[r] = bb;
  for (int k = 0; k < DD; ++k) {
    float w = W1[(size_t)k * DD + t];
    for (int r = 0; r < 8; ++r) acc[r] = fmaf(xs[r][k], w, acc[r]);
  }
  for (int r = 0; r < 8; ++r) {
    float s = dsc_wsum(acc[r]);
    if (lane == 0) red1[r][wid] = s;
  }
  __syncthreads();
  float g = ln_g[t];
  float be = ln_b[t];
  float mu[8];
  for (int r = 0; r < 8; ++r)
    mu[r] = (red1[r][0] + red1[r][1] + red1[r][2] + red1[r][3]) * (1.0f / 256.0f);
  for (int r = 0; r < 8; ++r) {
    float d = acc[r] - mu[r];
    float s = dsc_wsum(d * d);
    if (lane == 0) red2[r][wid] = s;
  }
  __syncthreads();
  for (int r = 0; r < 8; ++r) {
    float var = (red2[r][0] + red2[r][1] + red2[r][2] + red2[r][3]) * (1.0f / 256.0f);
    float hn = (acc[r] - mu[r]) / sqrtf(var + 1e-5f) * g + be;
    rs[r][t] = fmaxf(hn, 0.0f);
  }
  __syncthreads();

  const int j = t & 127;
  const int rb = (t >> 7) * 4;
  float f0 = b2[j];
  float f1 = f0, f2 = f0, f3 = f0;
  for (int k = 0; k < DD; ++k) {
    float w = W2[(size_t)k * D2 + j];
    f0 = fmaf(rs[rb + 0][k], w, f0);
    f1 = fmaf(rs[rb + 1][k], w, f1);
    f2 = fmaf(rs[rb + 2][k], w, f2);
    f3 = fmaf(rs[rb + 3][k], w, f3);
  }
  feat[(size_t)(row0 + rb + 0) * D2 + j] = f0;
  feat[(size_t)(row0 + rb + 1) * D2 + j] = f1;
  feat[(size_t)(row0 + rb + 2) * D2 + j] = f2;
  feat[(size_t)(row0 + rb + 3) * D2 + j] = f3;
}

// per-group clustering; grid 64, block 1024; fg + comp staged in dynamic LDS.
// Wave-parallel phases: softmax/argmax fused via width-8 shuffles; colsum/
// cnt/cn via 64-lane trees (cnt exact int; float trees = accepted ulp-level
// reordering). Dot products keep exact ascending order.
static __global__ __launch_bounds__(1024) void dsc_cluster(
    const float* feat, const float* comp, const float* temp, int* glob)
{
  extern __shared__ float dyn[];
  float* fgs = dyn;                 // [SS][LDSP]
  float* cgs = dyn + SS * LDSP;     // [SS][LDSP]

  __shared__ float Cc[KK][LDSP];
  __shared__ float pM[SS][KK + 1];
  __shared__ float nrm[SS];
  __shared__ float mind[SS];
  __shared__ int   asg[SS];
  __shared__ float cnp[KK][2];      // cn partials (2 waves per k)
  __shared__ float csp[KK][2];      // colsum partials
  __shared__ int   ctp[KK][2];      // cnt partials
  __shared__ float candv[2];
  __shared__ int   candi[2];
  __shared__ int   farp;

  const int t = threadIdx.x;
  const int gid = blockIdx.x;
  const float T = temp[0];
  const float* fg = feat + (size_t)gid * SS * D2;
  const float* cgp = comp + (size_t)(gid * SS) * NN + (size_t)gid * SS;

  // stage fg and the group's comp block into LDS (coalesced)
  for (int idx = t; idx < SS * D2; idx += 1024) {
    int i = idx >> 7, d = idx & 127;
    fgs[i * LDSP + d] = fg[idx];
  }
  for (int idx = t; idx < SS * SS; idx += 1024) {
    int i = idx >> 7, j = idx & 127;
    cgs[i * LDSP + j] = cgp[(size_t)i * NN + j];
  }
  __syncthreads();

  if (t < SS) {
    const float* row = fgs + t * LDSP;
    float s = 0.0f;
#pragma unroll 8
    for (int d = 0; d < D2; ++d) s = fmaf(row[d], row[d], s);
    nrm[t] = s;
    Cc[0][t] = fgs[t];  // center 0 = row 0
  }
  __syncthreads();

  // farthest-point init; sqrt'd distances exactly like the reference
  if (t < SS) {
    const float* row = fgs + t * LDSP;
    const float* frow = fgs;  // row 0
    float dot = 0.0f;
#pragma unroll 8
    for (int d = 0; d < D2; ++d) dot = fmaf(row[d], frow[d], dot);
    mind[t] = sqrtf(fmaxf(nrm[t] + nrm[0] - 2.0f * dot, 0.0f));
  }
  __syncthreads();
  for (int kk = 1; kk < KK; ++kk) {
    // parallel first-index argmax over mind (exact match to serial scan)
    if (t < SS) {
      float v = mind[t];
      int idx = t;
      for (int o = 1; o < 64; o <<= 1) {
        float ov = __shfl_xor(v, o);
        int oi = __shfl_xor(idx, o);
        if (ov > v || (ov == v && oi < idx)) { v = ov; idx = oi; }
      }
      if ((t & 63) == 0) { candv[t >> 6] = v; candi[t >> 6] = idx; }
    }
    __syncthreads();
    if (t == 0) farp = (candv[1] > candv[0]) ? candi[1] : candi[0];
    __syncthreads();
    const int fi = farp;
    if (t < SS) {
      const float* frow = fgs + fi * LDSP;
      Cc[kk][t] = frow[t];
      const float* row = fgs + t * LDSP;
      float dot = 0.0f;
#pragma unroll 8
      for (int d = 0; d < D2; ++d) dot = fmaf(row[d], frow[d], dot);
      float dd = sqrtf(fmaxf(nrm[t] + nrm[fi] - 2.0f * dot, 0.0f));
      if (dd < mind[t]) mind[t] = dd;
    }
    __syncthreads();
  }

  // initial cn partials: (k, d) layout, 64-lane tree per wave
  {
    const int kq = t >> 7, dq = t & 127;
    float c = Cc[kq][dq];
    float sq = c * c;
    for (int o = 1; o < 64; o <<= 1) sq += __shfl_xor(sq, o);
    if ((t & 63) == 0) cnp[kq][(t >> 6) & 1] = sq;
  }
  __syncthreads();

  const int ri = t >> 3;        // row for logits/q phases
  const int kc = t & 7;         // center for logits/q phases
  const int kq = t >> 7;        // k for reduction/update phases
  const int dq = t & 127;       // d (or i) for reduction/update phases
  for (int it = 0; it < CL_ITERS; ++it) {
    // B: logits + fused width-8 softmax
    float p;
    {
      float cnk = cnp[kc][0] + cnp[kc][1];
      const float* row = fgs + ri * LDSP;
      const float* cen = Cc[kc];
      float s = 0.0f;
#pragma unroll 8
      for (int d = 0; d < D2; ++d) s = fmaf(row[d], cen[d], s);
      float lg = -sqrtf(fmaxf(nrm[ri] + cnk - 2.0f * s, 0.0f)) / T;
      float m = lg;
      for (int o = 1; o < 8; o <<= 1) m = fmaxf(m, __shfl_xor(m, o, 8));
      float e = expf(lg - m);
      float es = e;
      for (int o = 1; o < 8; o <<= 1) es += __shfl_xor(es, o, 8);
      p = e / es;
      pM[ri][kc] = p;
    }
    __syncthreads();
    // D: colsum partials (k, i) layout
    {
      float v = pM[dq][kq];
      for (int o = 1; o < 64; o <<= 1) v += __shfl_xor(v, o);
      if ((t & 63) == 0) csp[kq][(t >> 6) & 1] = v;
    }
    __syncthreads();
    // E: q + row-normalize + first-index argmax (p carried in register)
    {
      float cs = csp[kc][0] + csp[kc][1] + 1e-6f;
      const float* crow = cgs + ri * LDSP;
      float dqv = 0.0f;
#pragma unroll 8
      for (int j = 0; j < SS; ++j) dqv = fmaf(crow[j], pM[j][kc], dqv);
      float q = p * expf(-(dqv / cs));
      float rsum = q;
      for (int o = 1; o < 8; o <<= 1) rsum += __shfl_xor(rsum, o, 8);
      rsum += 1e-6f;
      float v = q / rsum;
      int bk = kc;
      for (int o = 1; o < 8; o <<= 1) {
        float ov = __shfl_xor(v, o, 8);
        int ok = __shfl_xor(bk, o, 8);
        if (ov > v || (ov == v && ok < bk)) { v = ov; bk = ok; }
      }
      if (kc == 0) asg[ri] = bk;
    }
    __syncthreads();
    // G: cnt partials (k, i) layout -- integer tree (exact)
    {
      int c = (asg[dq] == kq) ? 1 : 0;
      for (int o = 1; o < 64; o <<= 1) c += __shfl_xor(c, o);
      if ((t & 63) == 0) ctp[kq][(t >> 6) & 1] = c;
    }
    __syncthreads();
    // H: center update (exact ascending-i predicated sum) + cn partials
    {
      int cnt = ctp[kq][0] + ctp[kq][1];
      float c;
      if (cnt > 0) {
        float s2 = 0.0f;
        for (int i = 0; i < SS; ++i) {
          float v = fgs[i * LDSP + dq];
          if (asg[i] == kq) s2 += v;
        }
        c = s2 / fmaxf((float)cnt, 1.0f);
        Cc[kq][dq] = c;
      } else {
        c = Cc[kq][dq];
      }
      float sq = c * c;
      for (int o = 1; o < 64; o <<= 1) sq += __shfl_xor(sq, o);
      if ((t & 63) == 0) cnp[kq][(t >> 6) & 1] = sq;
    }
    __syncthreads();
  }

  if (t < SS) glob[gid * SS + t] = asg[t] + gid * KK;
}

// labels: out[0..NN) = (float)glob[i]   -- OUTPUT IS FLOAT32
static __global__ void dsc_labels(const int* glob, float* out)
{
  int i = blockIdx.x * blockDim.x + threadIdx.x;
  if (i < NN) out[i] = (float)glob[i];
}

// P[i][j] = (glob[i]==glob[j]) ? 1.0f : 0.0f ; float4 stores, 8 rows/block.
// Skips f32-element window [e_lo, e_hi) (0,0 = disabled; fallback scratch).
static __global__ void dsc_pmat(const int* glob, float* out,
                                unsigned long long e_lo, unsigned long long e_hi)
{
  __shared__ __align__(8) unsigned short gl16[NN];  // 16 KB
  const int t = threadIdx.x;
  for (int i = t; i < NN; i += 256) gl16[i] = (unsigned short)glob[i];
  __syncthreads();
  const int row0 = blockIdx.x * 8;
  const uint2* gv = (const uint2*)gl16;  // 4 labels per uint2
  for (int r = 0; r < 8; ++r) {
    const int row = row0 + r;
    const unsigned int lab = (unsigned int)gl16[row];
    const unsigned long long ebase =
        (unsigned long long)NN + (unsigned long long)row * NN;
    for (int v = t; v < NN / 4; v += 256) {
      uint2 g4 = gv[v];
      float4 o;
      o.x = ((g4.x & 0xFFFFu) == lab) ? 1.0f : 0.0f;
      o.y = ((g4.x >> 16) == lab) ? 1.0f : 0.0f;
      o.z = ((g4.y & 0xFFFFu) == lab) ? 1.0f : 0.0f;
      o.w = ((g4.y >> 16) == lab) ? 1.0f : 0.0f;
      unsigned long long e = ebase + (unsigned long long)v * 4ull;
      if (!(e < e_hi && e + 4ull > e_lo)) {
        *(float4*)(out + e) = o;
      }
    }
  }
}

// fallback-only: patch the skip window (grid 1; glob snapshot in LDS first)
static __global__ void dsc_fix(const int* glob, float* out,
                               unsigned long long e_lo, unsigned long long e_hi)
{
  __shared__ int gl[NN];  // 32 KB
  const int t = threadIdx.x;
  for (int i = t; i < NN; i += 256) gl[i] = glob[i];
  __syncthreads();
  for (unsigned long long e = e_lo + (unsigned long long)t; e < e_hi; e += 256ull) {
    if (e < (unsigned long long)NN) {
      out[e] = (float)gl[e];
    } else {
      unsigned long long pf = e - (unsigned long long)NN;
      int i = (int)(pf >> 13);
      int j = (int)(pf & 8191ull);
      out[e] = (gl[i] == gl[j]) ? 1.0f : 0.0f;
    }
  }
}

extern "C" void kernel_launch(void* const* d_in, const int* in_sizes, int n_in,
                              void* d_out, int out_size, void* d_ws, size_t ws_size,
                              hipStream_t stream) {
  (void)in_sizes;
  (void)n_in;
  const float* x    = (const float*)d_in[0];
  // d_in[1] = lv_group_ids: unused by the reference computation
  const float* comp = (const float*)d_in[2];
  const float* W1   = (const float*)d_in[3];
  const float* b1   = (const float*)d_in[4];
  const float* ln_g = (const float*)d_in[5];
  const float* ln_b = (const float*)d_in[6];
  const float* W2   = (const float*)d_in[7];
  const float* b2   = (const float*)d_in[8];
  const float* temp = (const float*)d_in[9];

  float* out = (float*)d_out;                       // FLOAT32 output buffer
  char* outc = (char*)d_out;
  const size_t out_bytes  = (size_t)out_size * 4u;  // f32: ~268 MB
  const size_t feat_bytes = (size_t)NN * D2 * 4u;   // 4 MB
  const size_t glob_bytes = (size_t)NN * 4u;        // 32 KB
  const size_t scratch_bytes = feat_bytes + glob_bytes;

  float* feat;
  int* glob;
  unsigned long long e_lo = 0ull, e_hi = 0ull;
  int need_fix = 0;
  if (ws_size >= scratch_bytes) {
    feat = (float*)d_ws;
    glob = (int*)((char*)d_ws + feat_bytes);
  } else {
    // carve from d_out's tail; pmat skips the glob window, dsc_fix patches it
    feat = (float*)(outc + out_bytes - glob_bytes - feat_bytes);
    glob = (int*)(outc + out_bytes - glob_bytes);
    e_lo = (unsigned long long)(out_size - NN);
    e_hi = (unsigned long long)out_size;
    need_fix = 1;
  }

  const size_t dyn_lds = (size_t)(2 * SS * LDSP) * sizeof(float);  // 132096 B

  dsc_mlp<<<NN / 8, 256, 0, stream>>>(x, W1, b1, ln_g, ln_b, W2, b2, feat);
  dsc_cluster<<<GG, 1024, dyn_lds, stream>>>(feat, comp, temp, glob);
  dsc_labels<<<(NN + 255) / 256, 256, 0, stream>>>(glob, out);
  dsc_pmat<<<NN / 8, 256, 0, stream>>>(glob, out, e_lo, e_hi);
  if (need_fix) {
    dsc_fix<<<1, 256, 0, stream>>>(glob, out, e_lo, e_hi);
  }
}